// Round 16
// baseline (357.673 us; speedup 1.0000x reference)
//
#include <hip/hip_runtime.h>
#include <hip/hip_bf16.h>

// HCNet: L=4 hyper-connection blocks, N=4, D=2048, B*T=4096 tokens.
// R16: shared-table dots moved to the MFMA pipe. table_dots computes
// TD[tok][48] = h2 @ [ones|gwm|gwr|gwb] as a skinny GEMM (full B-reuse,
// fixing R8's per-token-operand failure). fused_dw phase-1 keeps only the
// per-token Gram dots; Tb/Pn/o become scalar TD reads. gemm/width0/
// depth_last = R15 champion config.

#define DD 2048
#define NN 4
#define LL 4
#define NTOK 4096
#define EPSF 1e-5f
#define STS 80  // ST row stride (floats)

typedef __attribute__((ext_vector_type(8))) short bf16x8;
typedef __attribute__((ext_vector_type(4))) float f32x4;
typedef __attribute__((ext_vector_type(2))) float f32x2;

__device__ __forceinline__ float bf2f(short u) {
  union { unsigned int i; float f; } v;
  v.i = ((unsigned int)(unsigned short)u) << 16;
  return v.f;
}
__device__ __forceinline__ short f2bf(float f) {
  __hip_bfloat16 h = __float2bfloat16(f);
  short s;
  __builtin_memcpy(&s, &h, 2);
  return s;
}
__device__ __forceinline__ float wred(float v) {
#pragma unroll
  for (int off = 32; off > 0; off >>= 1) v += __shfl_xor(v, off, 64);
  return v;
}
__device__ __forceinline__ void ld16(const void* g, void* l) {
  __builtin_amdgcn_global_load_lds(
      (const __attribute__((address_space(1))) void*)g,
      (__attribute__((address_space(3))) void*)l, 16, 0, 0);
}
__host__ __device__ constexpr int pofs(int k, int l) {
  return k == 0 ? 20 + l * 5
       : k == 1 ? 40 + (l - 1) * 5
       : k == 2 ? 55 + (l - 2) * 5
                : 65;
}

// ---------------- prep: gamma-scaled bf16 tables + beta/gamma ratio ---------
__global__ __launch_bounds__(256) void prep_pack(
    const float* __restrict__ W_m, const float* __restrict__ W_r,
    const float* __restrict__ W_b, const float* __restrict__ dyn_gamma,
    const float* __restrict__ norm_gamma, const float* __restrict__ norm_beta,
    short* __restrict__ gwm, short* __restrict__ gwr, short* __restrict__ gwb,
    float* __restrict__ rb) {
  const int i = blockIdx.x * 256 + threadIdx.x;  // over L*D = 8192
  const float g = dyn_gamma[i];
  gwm[i] = f2bf(g * W_m[i]);
  f32x4 r = *(const f32x4*)(W_r + (size_t)i * 4);
  f32x4 b = *(const f32x4*)(W_b + (size_t)i * 4);
  short ro[4], bo[4];
#pragma unroll
  for (int k = 0; k < 4; k++) { ro[k] = f2bf(g * r[k]); bo[k] = f2bf(g * b[k]); }
  *(unsigned long long*)(gwr + (size_t)i * 4) = *(unsigned long long*)ro;
  *(unsigned long long*)(gwb + (size_t)i * 4) = *(unsigned long long*)bo;
  rb[i] = norm_beta[i] / norm_gamma[i];
}

// ------- build MFMA B-fragment table: 48 cols = [1|gwm 1..4|gwr 5..20|gwb 21..36|0]
// entry (g,kt,lane): value[j] = col(g*16+lane&15) at k = kt*32+(lane>>4)*8+j
__global__ __launch_bounds__(256) void prep_tmf(
    const short* __restrict__ gwm, const short* __restrict__ gwr,
    const short* __restrict__ gwb, short* __restrict__ TMf) {
  const int g = blockIdx.y;                            // 0..2
  const int kt = blockIdx.x * 4 + (threadIdx.x >> 6);  // 0..63
  const int lane = threadIdx.x & 63;
  const int col = g * 16 + (lane & 15);
  const int k0 = kt * 32 + (lane >> 4) * 8;
  short v[8];
#pragma unroll
  for (int j = 0; j < 8; j++) {
    const int k = k0 + j;
    short x = 0;
    if (col == 0) x = (short)0x3F80;  // bf16 1.0
    else if (col <= 4) x = gwm[(col - 1) * DD + k];
    else if (col <= 20) {
      const int t = col - 5;
      x = gwr[((size_t)(t >> 2) * DD + k) * 4 + (t & 3)];
    } else if (col <= 36) {
      const int t = col - 21;
      x = gwb[((size_t)(t >> 2) * DD + k) * 4 + (t & 3)];
    }
    v[j] = x;
  }
  *(bf16x8*)(TMf + (size_t)((g * 64 + kt) * 64 + lane) * 8) = *(bf16x8*)v;
}

// ------- table_dots: TD[tok][48] = v[tok][:] . TM[:,48]  (skinny MFMA GEMM) -
// 1 wave per block, 16 tokens per wave; B-frags shared (full reuse).
__global__ __launch_bounds__(64) void table_dots(
    const short* __restrict__ v, const short* __restrict__ TMf,
    float* __restrict__ TD) {
  const int lane = threadIdx.x & 63;
  const int tok0 = blockIdx.x * 16;
  const char* ap = (const char*)(v + (size_t)(tok0 + (lane & 15)) * DD +
                                 (lane >> 4) * 8);
  f32x4 ac0 = {}, ac1 = {}, ac2 = {};
#pragma unroll 4
  for (int kt = 0; kt < 64; ++kt) {
    bf16x8 a = *(const bf16x8*)(ap + kt * 64);
    bf16x8 b0 = *(const bf16x8*)((const char*)TMf +
                                 (size_t)((0 * 64 + kt) * 64 + lane) * 16);
    bf16x8 b1 = *(const bf16x8*)((const char*)TMf +
                                 (size_t)((1 * 64 + kt) * 64 + lane) * 16);
    bf16x8 b2 = *(const bf16x8*)((const char*)TMf +
                                 (size_t)((2 * 64 + kt) * 64 + lane) * 16);
    ac0 = __builtin_amdgcn_mfma_f32_16x16x32_bf16(a, b0, ac0, 0, 0, 0);
    ac1 = __builtin_amdgcn_mfma_f32_16x16x32_bf16(a, b1, ac1, 0, 0, 0);
    ac2 = __builtin_amdgcn_mfma_f32_16x16x32_bf16(a, b2, ac2, 0, 0, 0);
  }
  const int trow = tok0 + ((lane >> 4) << 2);
  const int c = lane & 15;
#pragma unroll
  for (int j = 0; j < 4; j++) {
    TD[(size_t)(trow + j) * 48 + c] = ac0[j];
    TD[(size_t)(trow + j) * 48 + 16 + c] = ac1[j];
    TD[(size_t)(trow + j) * 48 + 32 + c] = ac2[j];
  }
}

// ---------------- token-independent sums S0w[l][5], T0d[l][4] ---------------
__global__ __launch_bounds__(64) void prep_sums(
    const float* __restrict__ W_m, const float* __restrict__ W_r,
    const float* __restrict__ W_b, const float* __restrict__ dyn_gamma,
    float* __restrict__ S0w, float* __restrict__ T0d) {
  const int l = blockIdx.x;
  const int lane = threadIdx.x;
  float s[5] = {0, 0, 0, 0, 0}, t[4] = {0, 0, 0, 0};
  for (int d = lane; d < DD; d += 64) {
    const float g = dyn_gamma[l * DD + d];
    s[0] += g * W_m[l * DD + d];
    f32x4 r = *(const f32x4*)(W_r + ((size_t)l * DD + d) * 4);
    f32x4 b = *(const f32x4*)(W_b + ((size_t)l * DD + d) * 4);
#pragma unroll
    for (int m = 0; m < 4; m++) { s[1 + m] += g * r[m]; t[m] += g * b[m]; }
  }
#pragma unroll
  for (int m = 0; m < 5; m++) s[m] = wred(s[m]);
#pragma unroll
  for (int n = 0; n < 4; n++) t[n] = wred(t[n]);
  if (lane == 0) {
#pragma unroll
    for (int m = 0; m < 5; m++) S0w[l * 5 + m] = s[m];
#pragma unroll
    for (int n = 0; n < 4; n++) T0d[l * 4 + n] = t[n];
  }
}

// ------- transpose Wblk[l][d][e] (f32) -> Wt[l][e][d] = norm_g[d]*W (bf16) --
__global__ __launch_bounds__(256) void transpose_wblk(
    const float* __restrict__ W, const float* __restrict__ norm_gamma,
    short* __restrict__ Wt) {
  __shared__ float tile[64][65];
  const int blk = blockIdx.z;
  const int c0 = blockIdx.x * 64;
  const int r0 = blockIdx.y * 64;
  const float* Ws = W + (size_t)blk * DD * DD;
  short* Wd = Wt + (size_t)blk * DD * DD;
  const int tx = threadIdx.x & 63, ty = threadIdx.x >> 6;
#pragma unroll
  for (int r = 0; r < 16; r++) {
    const int row = ty + r * 4;
    tile[row][tx] = Ws[(size_t)(r0 + row) * DD + c0 + tx];
  }
  const float gsc = norm_gamma[blk * DD + r0 + tx];
  __syncthreads();
#pragma unroll
  for (int r = 0; r < 16; r++) {
    const int row = ty + r * 4;
    Wd[(size_t)(c0 + row) * DD + r0 + tx] = f2bf(tile[tx][row] * gsc);
  }
}

// ---------------- row sums of Wt': E1 = sum_d Wt', E0 = sum_d rb*Wt' + bias -
__global__ __launch_bounds__(256) void row_sums(
    const short* __restrict__ Wt, const float* __restrict__ rb,
    const float* __restrict__ bblk, float* __restrict__ E0,
    float* __restrict__ E1) {
  const int l = blockIdx.y;
  const int e = blockIdx.x * 4 + (threadIdx.x >> 6);
  const int lane = threadIdx.x & 63;
  const short* row = Wt + ((size_t)l * DD + e) * DD;
  const float* rbl = rb + l * DD;
  float s1 = 0.f, s0 = 0.f;
#pragma unroll
  for (int it = 0; it < 4; it++) {
    const int d0 = lane * 8 + it * 512;
    bf16x8 w = *(const bf16x8*)(row + d0);
    f32x4 r0 = *(const f32x4*)(rbl + d0), r1 = *(const f32x4*)(rbl + d0 + 4);
#pragma unroll
    for (int q = 0; q < 8; q++) {
      const float wq = bf2f(w[q]);
      s1 += wq;
      s0 += wq * ((q < 4) ? r0[q] : r1[q - 4]);
    }
  }
  s1 = wred(s1); s0 = wred(s0);
  if (lane == 0) {
    E1[l * DD + e] = s1;
    E0[l * DD + e] = s0 + bblk[l * DD + e];
  }
}

// ---------------- width0: x-dots + block-0 coefficients + hnorm -------------
__global__ __launch_bounds__(256) void width0_kernel(
    const float* __restrict__ x, short* __restrict__ b0,
    short* __restrict__ hout, f32x2* __restrict__ tst, float* __restrict__ Cc,
    float* __restrict__ ST, const float* __restrict__ A_m,
    const float* __restrict__ A_r, const short* __restrict__ gwm,
    const short* __restrict__ gwr, const float* __restrict__ s_a,
    const float* __restrict__ S0w) {
  const int wave = threadIdx.x >> 6;
  const int lane = threadIdx.x & 63;
  const int tok = blockIdx.x * 4 + wave;
  const float* xr = x + (size_t)tok * DD;
  short* b0t = b0 + (size_t)tok * DD;

  bf16x8 xb[4];
#pragma unroll
  for (int j = 0; j < 4; j++) {
    const int d0 = lane * 8 + j * 512;
    f32x4 a = *(const f32x4*)(xr + d0);
    f32x4 b = *(const f32x4*)(xr + d0 + 4);
    bf16x8 p;
#pragma unroll
    for (int q = 0; q < 4; q++) { p[q] = f2bf(a[q]); p[4 + q] = f2bf(b[q]); }
    xb[j] = p;
    *(bf16x8*)(b0t + d0) = p;
  }

  float o = 0.f, qq = 0.f, P0[4][5];
#pragma unroll
  for (int l = 0; l < 4; l++)
#pragma unroll
    for (int m = 0; m < 5; m++) P0[l][m] = 0.f;

#pragma unroll
  for (int j = 0; j < 4; j++) {
    const int d0 = lane * 8 + j * 512;
    bf16x8 wmv[4], wrv[4][4];
#pragma unroll
    for (int l = 0; l < 4; l++) {
      wmv[l] = *(const bf16x8*)(gwm + l * DD + d0);
#pragma unroll
      for (int p = 0; p < 4; p++)
        wrv[l][p] = *(const bf16x8*)(gwr + ((size_t)l * DD + d0 + 2 * p) * 4);
    }
#pragma unroll
    for (int q = 0; q < 8; q++) {
      const float hv = bf2f(xb[j][q]);
      o += hv; qq += hv * hv;
#pragma unroll
      for (int l = 0; l < 4; l++) {
        P0[l][0] += hv * bf2f(wmv[l][q]);
#pragma unroll
        for (int m = 0; m < 4; m++)
          P0[l][1 + m] += hv * bf2f(wrv[l][q >> 1][(q & 1) * 4 + m]);
      }
    }
  }
  o = wred(o); qq = wred(qq);
#pragma unroll
  for (int l = 0; l < 4; l++)
#pragma unroll
    for (int m = 0; m < 5; m++) P0[l][m] = wred(P0[l][m]);

  // block-0 width coefficients (all H rows = x)
  const float sa = s_a[0];
  const float mu = o * (1.f / DD);
  const float inv = rsqrtf(qq * (1.f / DD) - mu * mu + EPSF);
  const float t0 = tanhf(inv * (P0[0][0] - mu * S0w[0]));
  float tm[4];
#pragma unroll
  for (int m = 0; m < 4; m++)
    tm[m] = tanhf(inv * (P0[0][1 + m] - mu * S0w[1 + m]));
  float amSum = 0.f, arCol[4] = {0, 0, 0, 0};
#pragma unroll
  for (int n = 0; n < 4; n++) {
    amSum += A_m[n] + sa * t0;
#pragma unroll
    for (int m = 0; m < 4; m++) arCol[m] += A_r[n * 4 + m] + sa * tm[m];
  }

  if (lane == 0) {
    const float sh = amSum * o;
    const float sh2 = amSum * amSum * qq;
    const float mu2 = sh * (1.f / DD);
    const float inv2 = rsqrtf(sh2 * (1.f / DD) - mu2 * mu2 + EPSF);
    f32x2 t; t[0] = inv2; t[1] = mu2 * inv2;
    tst[tok] = t;
    float* STt = ST + (size_t)tok * STS;
    STt[0] = o;
    STt[4] = qq;  // G[0][0]
#pragma unroll
    for (int l = 0; l < 4; l++)
#pragma unroll
      for (int m = 0; m < 5; m++) STt[pofs(0, l) + m] = P0[l][m];
    float* Ct = Cc + (size_t)tok * 16;
#pragma unroll
    for (int n = 0; n < 4; n++) Ct[n * 4] = arCol[n];
  }

  short* hw = hout + (size_t)tok * DD;
#pragma unroll
  for (int j = 0; j < 4; j++) {
    const int d0 = lane * 8 + j * 512;
    bf16x8 ho;
#pragma unroll
    for (int q = 0; q < 8; q++) ho[q] = f2bf(amSum * bf2f(xb[j][q]));
    *(bf16x8*)(hw + d0) = ho;
  }
}

// ---------------- block GEMM: h2 = LN-folded(h @ Wt') -----------------------
__global__ __launch_bounds__(512) void gemm_kernel(
    const short* __restrict__ A, const short* __restrict__ Bt,
    const f32x2* __restrict__ tst, const float* __restrict__ E0,
    const float* __restrict__ E1, short* __restrict__ C) {
  __shared__ short lA[2][128 * 64];
  __shared__ short lB[2][128 * 64];
  const int tid = threadIdx.x;
  const int lane = tid & 63;
  const int wave = tid >> 6;
  const int bid = blockIdx.x;
  const int wg = (bid & 7) * 64 + (bid >> 3);
  const int m0 = (wg & 31) * 128, n0 = (wg >> 5) * 128;
  const int wm = wave >> 2;
  const int wn = wave & 3;

  f32x4 acc[4][2] = {};

#define STAGE(buf, kt)                                                        \
  {                                                                           \
    const int k0 = (kt) * 64;                                                 \
    _Pragma("unroll") for (int c = 0; c < 2; c++) {                           \
      const int idx = c * 512 + tid;                                          \
      const int row = idx >> 3;                                               \
      const int colsw = (((idx & 7) ^ (row & 7)) * 8);                        \
      ld16(A + (size_t)(m0 + row) * DD + k0 + colsw,                          \
           (char*)&lA[buf][0] + idx * 16);                                    \
      ld16(Bt + (size_t)(n0 + row) * DD + k0 + colsw,                         \
           (char*)&lB[buf][0] + idx * 16);                                    \
    }                                                                         \
  }

#define COMPUTE(cur)                                                          \
  {                                                                           \
    const char* bufA = (const char*)&lA[cur][0];                              \
    const char* bufB = (const char*)&lB[cur][0];                              \
    _Pragma("unroll") for (int kk = 0; kk < 2; ++kk) {                        \
      const int gsw = (kk * 64 + (lane >> 4) * 16) ^ ((lane & 7) << 4);       \
      bf16x8 af[4], bfr[2];                                                   \
      _Pragma("unroll") for (int m = 0; m < 4; m++) {                         \
        const int r = wm * 64 + m * 16 + (lane & 15);                         \
        af[m] = *(const bf16x8*)(bufA + r * 128 + gsw);                       \
      }                                                                       \
      _Pragma("unroll") for (int n = 0; n < 2; n++) {                         \
        const int r = wn * 32 + n * 16 + (lane & 15);                         \
        bfr[n] = *(const bf16x8*)(bufB + r * 128 + gsw);                      \
      }                                                                       \
      __builtin_amdgcn_s_setprio(1);                                          \
      _Pragma("unroll") for (int m = 0; m < 4; m++)                           \
        _Pragma("unroll") for (int n = 0; n < 2; n++)                         \
          acc[m][n] = __builtin_amdgcn_mfma_f32_16x16x32_bf16(                \
              af[m], bfr[n], acc[m][n], 0, 0, 0);                             \
      __builtin_amdgcn_s_setprio(0);                                          \
    }                                                                         \
  }

  STAGE(0, 0);
  for (int kt = 0; kt < 31; ++kt) {
    const int cur = kt & 1;
    STAGE(cur ^ 1, kt + 1);                       // 4 loads -> 8 outstanding
    asm volatile("s_waitcnt vmcnt(4)" ::: "memory");  // stage(kt) landed
    asm volatile("s_barrier" ::: "memory");           // all waves agree
    COMPUTE(cur);
    asm volatile("s_barrier" ::: "memory");           // reads of buf cur done
  }
  asm volatile("s_waitcnt vmcnt(0)" ::: "memory");
  asm volatile("s_barrier" ::: "memory");
  COMPUTE(1);
#undef STAGE
#undef COMPUTE

  float e0c[2], e1c[2];
  int cols[2];
#pragma unroll
  for (int n = 0; n < 2; n++) {
    cols[n] = n0 + wn * 32 + n * 16 + (lane & 15);
    e0c[n] = E0[cols[n]];
    e1c[n] = E1[cols[n]];
  }
#pragma unroll
  for (int m = 0; m < 4; m++) {
    const int rbase = m0 + wm * 64 + m * 16 + ((lane >> 4) << 2);
#pragma unroll
    for (int j = 0; j < 4; j++) {
      const int row = rbase + j;
      const f32x2 iv = tst[row];
#pragma unroll
      for (int n = 0; n < 2; n++)
        C[(size_t)row * DD + cols[n]] =
            f2bf(iv[0] * acc[m][n][j] - iv[1] * e1c[n] + e0c[n]);
    }
  }
}

// ------- fused depth(I)+width(I+1), basis form, slim (table dots from TD) ---
template <int I>
__global__ __launch_bounds__(256) void fused_dw(
    const short* __restrict__ h2s, const short* __restrict__ b0,
    short* __restrict__ hout, f32x2* __restrict__ tst, float* __restrict__ Cc,
    float* __restrict__ ST, const float* __restrict__ TDs,
    const float* __restrict__ Bp, const float* __restrict__ s_b,
    const float* __restrict__ A_m, const float* __restrict__ A_r,
    const float* __restrict__ s_a, const float* __restrict__ S0w,
    const float* __restrict__ T0d) {
  constexpr int NB = I + 1;   // width block index
  const int wave = threadIdx.x >> 6;
  const int lane = threadIdx.x & 63;
  const int tok = blockIdx.x * 4 + wave;

  const short* vt = h2s + ((size_t)I * NTOK + tok) * DD;
  const short* bases[I + 1];
  bases[0] = b0 + (size_t)tok * DD;
#pragma unroll
  for (int k = 1; k <= I; k++)
    bases[k] = h2s + ((size_t)(k - 1) * NTOK + tok) * DD;

  bf16x8 h2r[4];
#pragma unroll
  for (int j = 0; j < 4; j++)
    h2r[j] = *(const bf16x8*)(vt + lane * 8 + j * 512);

  // ---- phase 1: Gram dots only (per-token, must stay VALU) ----
  float Gr[I + 2] = {};   // Gr[k]=v.b_k (k<=I), Gr[I+1]=v.v
#pragma unroll
  for (int j = 0; j < 4; j++) {
    const int d0 = lane * 8 + j * 512;
    bf16x8 bsv[I + 1];
#pragma unroll
    for (int k = 0; k <= I; k++) bsv[k] = *(const bf16x8*)(bases[k] + d0);
#pragma unroll
    for (int q = 0; q < 8; q++) {
      const float hv = bf2f(h2r[j][q]);
      Gr[I + 1] += hv * hv;
#pragma unroll
      for (int k = 0; k <= I; k++) Gr[k] += hv * bf2f(bsv[k][q]);
    }
  }
#pragma unroll
  for (int k = 0; k <= I + 1; k++) Gr[k] = wred(Gr[k]);

  // ---- phase 2: coefficient algebra; table dots read from TD slots ----
  float* STt = ST + (size_t)tok * STS;
  float* Ct = Cc + (size_t)tok * 16;
  const float* TDt[I + 1];  // TDt[k] = dots of h2^k (= basis b_{k+1})
#pragma unroll
  for (int k = 0; k <= I; k++)
    TDt[k] = TDs + ((size_t)k * NTOK + tok) * 48;

  float ofull[I + 2], Gf[I + 2][I + 2], Pf[I + 2][5], Cp[4][I + 2];
  ofull[0] = STt[0];
#pragma unroll
  for (int k = 1; k <= I + 1; k++) ofull[k] = TDt[k - 1][0];
#pragma unroll
  for (int k = 0; k <= I; k++)
#pragma unroll
    for (int j2 = 0; j2 <= I; j2++) Gf[k][j2] = STt[4 + k * 4 + j2];
#pragma unroll
  for (int k = 0; k <= I; k++) { Gf[k][I + 1] = Gr[k]; Gf[I + 1][k] = Gr[k]; }
  Gf[I + 1][I + 1] = Gr[I + 1];
#pragma unroll
  for (int m = 0; m < 5; m++) Pf[0][m] = STt[pofs(0, NB) + m];
#pragma unroll
  for (int k = 1; k <= I + 1; k++) {
    Pf[k][0] = TDt[k - 1][1 + NB];
#pragma unroll
    for (int m = 0; m < 4; m++) Pf[k][1 + m] = TDt[k - 1][5 + NB * 4 + m];
  }
  float Tb[4];
#pragma unroll
  for (int n = 0; n < 4; n++) Tb[n] = TDt[I][21 + I * 4 + n];
#pragma unroll
  for (int n = 0; n < 4; n++)
#pragma unroll
    for (int k = 0; k <= I; k++) Cp[n][k] = Ct[n * 4 + k];

  // depth coefficients Bv (block I)
  {
    const float o_ = ofull[I + 1];
    const float mu2 = o_ * (1.f / DD);
    const float inv2 = rsqrtf(Gr[I + 1] * (1.f / DD) - mu2 * mu2 + EPSF);
    const float sb = s_b[I];
#pragma unroll
    for (int n = 0; n < 4; n++)
      Cp[n][I + 1] = Bp[I * 4 + n] +
                     sb * tanhf(inv2 * (Tb[n] - mu2 * T0d[I * 4 + n]));
  }

  // width coefficients Am/Ar (block NB) from Gram-expanded stats
  const float sa = s_a[NB];
  float Am[4], Ar[4][4];
#pragma unroll
  for (int n = 0; n < 4; n++) {
    float sH = 0.f, sH2 = 0.f;
#pragma unroll
    for (int k = 0; k <= I + 1; k++) {
      sH += Cp[n][k] * ofull[k];
#pragma unroll
      for (int j2 = 0; j2 <= I + 1; j2++)
        sH2 += Cp[n][k] * Cp[n][j2] * Gf[k][j2];
    }
    const float mu = sH * (1.f / DD);
    const float inv = rsqrtf(sH2 * (1.f / DD) - mu * mu + EPSF);
    float S1[5];
#pragma unroll
    for (int m = 0; m < 5; m++) {
      S1[m] = 0.f;
#pragma unroll
      for (int k = 0; k <= I + 1; k++) S1[m] += Cp[n][k] * Pf[k][m];
    }
    Am[n] = A_m[NB * 4 + n] +
            sa * tanhf(inv * (S1[0] - mu * S0w[NB * 5 + 0]));
#pragma unroll
    for (int m = 0; m < 4; m++)
      Ar[n][m] = A_r[NB * 16 + n * 4 + m] +
                 sa * tanhf(inv * (S1[1 + m] - mu * S0w[NB * 5 + 1 + m]));
  }

  // new coefficient matrix and hnorm combo coefficients
  float Cn[4][I + 2], hc[I + 2];
#pragma unroll
  for (int k = 0; k <= I + 1; k++) {
    hc[k] = 0.f;
#pragma unroll
    for (int n = 0; n < 4; n++) hc[k] += Am[n] * Cp[n][k];
  }
#pragma unroll
  for (int mr = 0; mr < 4; mr++)
#pragma unroll
    for (int k = 0; k <= I + 1; k++) {
      float acc = 0.f;
#pragma unroll
      for (int n = 0; n < 4; n++) acc += Ar[n][mr] * Cp[n][k];
      Cn[mr][k] = acc;
    }

  if (lane == 0) {
    float sh = 0.f, sh2 = 0.f;
#pragma unroll
    for (int k = 0; k <= I + 1; k++) {
      sh += hc[k] * ofull[k];
#pragma unroll
      for (int j2 = 0; j2 <= I + 1; j2++) sh2 += hc[k] * hc[j2] * Gf[k][j2];
    }
    const float mu = sh * (1.f / DD);
    const float inv = rsqrtf(sh2 * (1.f / DD) - mu * mu + EPSF);
    f32x2 t; t[0] = inv; t[1] = mu * inv;
    tst[tok] = t;
    // forward Gram row I+1 (P and o forwarding now via TD slots)
#pragma unroll
    for (int k = 0; k <= I + 1; k++) {
      STt[4 + (I + 1) * 4 + k] = Gf[I + 1][k];
      STt[4 + k * 4 + (I + 1)] = Gf[k][I + 1];
    }
#pragma unroll
    for (int n = 0; n < 4; n++)
#pragma unroll
      for (int k = 0; k <= I + 1; k++) Ct[n * 4 + k] = Cn[n][k];
  }

  // ---- phase 3: hnorm = sum_k hc[k] * b_k ----
  short* hw = hout + (size_t)tok * DD;
#pragma unroll
  for (int j = 0; j < 4; j++) {
    const int d0 = lane * 8 + j * 512;
    bf16x8 bsv[I + 1];
#pragma unroll
    for (int k = 0; k <= I; k++) bsv[k] = *(const bf16x8*)(bases[k] + d0);
    bf16x8 ho;
#pragma unroll
    for (int q = 0; q < 8; q++) {
      float a = hc[I + 1] * bf2f(h2r[j][q]);
#pragma unroll
      for (int k = 0; k <= I; k++) a += hc[k] * bf2f(bsv[k][q]);
      ho[q] = f2bf(a);
    }
    *(bf16x8*)(hw + d0) = ho;
  }
}

// ---------------- final depth (block 3) + output combo ----------------------
__global__ __launch_bounds__(256) void depth_last(
    const short* __restrict__ h2s, const short* __restrict__ b0,
    float* __restrict__ out, const float* __restrict__ Cc,
    const float* __restrict__ Bp, const float* __restrict__ s_b,
    const float* __restrict__ T0d, const short* __restrict__ gwb) {
  const int wave = threadIdx.x >> 6;
  const int lane = threadIdx.x & 63;
  const int tok = blockIdx.x * 4 + wave;
  const short* vt = h2s + ((size_t)3 * NTOK + tok) * DD;

  bf16x8 h2r[4];
  float s1 = 0.f, s2 = 0.f, Tb[4] = {0, 0, 0, 0};
#pragma unroll
  for (int j = 0; j < 4; j++) {
    const int d0 = lane * 8 + j * 512;
    h2r[j] = *(const bf16x8*)(vt + d0);
    bf16x8 wbv[4];
#pragma unroll
    for (int p = 0; p < 4; p++)
      wbv[p] = *(const bf16x8*)(gwb + ((size_t)3 * DD + d0 + 2 * p) * 4);
#pragma unroll
    for (int q = 0; q < 8; q++) {
      const float hv = bf2f(h2r[j][q]);
      s1 += hv; s2 += hv * hv;
#pragma unroll
      for (int n = 0; n < 4; n++)
        Tb[n] += hv * bf2f(wbv[q >> 1][(q & 1) * 4 + n]);
    }
  }
  s1 = wred(s1); s2 = wred(s2);
#pragma unroll
  for (int n = 0; n < 4; n++) Tb[n] = wred(Tb[n]);

  const float mu = s1 * (1.f / DD);
  const float inv = rsqrtf(s2 * (1.f / DD) - mu * mu + EPSF);
  const float sb = s_b[3];
  float bsum = 0.f;
#pragma unroll
  for (int n = 0; n < 4; n++)
    bsum += Bp[12 + n] + sb * tanhf(inv * (Tb[n] - mu * T0d[12 + n]));

  const float* Ct = Cc + (size_t)tok * 16;
  float e[4];
#pragma unroll
  for (int k = 0; k < 4; k++) {
    e[k] = 0.f;
#pragma unroll
    for (int n = 0; n < 4; n++) e[k] += Ct[n * 4 + k];
  }

  const short* bases[4];
  bases[0] = b0 + (size_t)tok * DD;
#pragma unroll
  for (int k = 1; k < 4; k++)
    bases[k] = h2s + ((size_t)(k - 1) * NTOK + tok) * DD;

  float* orow = out + (size_t)tok * DD;
#pragma unroll
  for (int j = 0; j < 4; j++) {
    const int d0 = lane * 8 + j * 512;
    bf16x8 bsv[4];
#pragma unroll
    for (int k = 0; k < 4; k++) bsv[k] = *(const bf16x8*)(bases[k] + d0);
    f32x4 o0, o1;
#pragma unroll
    for (int q = 0; q < 8; q++) {
      float s = bsum * bf2f(h2r[j][q]);
#pragma unroll
      for (int k = 0; k < 4; k++) s += e[k] * bf2f(bsv[k][q]);
      if (q < 4) o0[q] = s; else o1[q - 4] = s;
    }
    *(f32x4*)(orow + d0) = o0;
    *(f32x4*)(orow + d0 + 4) = o1;
  }
}

extern "C" void kernel_launch(void* const* d_in, const int* in_sizes, int n_in,
                              void* d_out, int out_size, void* d_ws,
                              size_t ws_size, hipStream_t stream) {
  const float* x = (const float*)d_in[0];
  const float* A_m = (const float*)d_in[1];
  const float* A_r = (const float*)d_in[2];
  const float* Bp = (const float*)d_in[3];
  const float* W_m = (const float*)d_in[4];
  const float* W_r = (const float*)d_in[5];
  const float* W_b = (const float*)d_in[6];
  const float* s_a = (const float*)d_in[7];
  const float* s_b = (const float*)d_in[8];
  const float* dyn_gamma = (const float*)d_in[9];
  const float* norm_gamma = (const float*)d_in[10];
  const float* norm_beta = (const float*)d_in[11];
  const float* Wblk = (const float*)d_in[12];
  const float* bblk = (const float*)d_in[13];
  float* out = (float*)d_out;

  char* ws = (char*)d_ws;
  short* b0 = (short*)(ws);                    // 16 MiB: bf16 copy of x
  short* h2s = (short*)(ws + 16777216);        // 4 slots x 16 MiB
  short* hnorm = (short*)(ws + 83886080);      // 16 MiB
  char* aux = ws + 100663296;
  short* gwm = (short*)(aux);                  // 16 KiB
  short* gwr = (short*)(aux + 16384);          // 64 KiB
  short* gwb = (short*)(aux + 81920);          // 64 KiB
  float* rb = (float*)(aux + 147456);          // 32 KiB
  float* S0w = (float*)(aux + 180224);
  float* T0d = (float*)(aux + 181248);
  f32x2* tst = (f32x2*)(aux + 182272);         // 32 KiB
  float* E0 = (float*)(aux + 215040);          // 32 KiB
  float* E1 = (float*)(aux + 247808);          // 32 KiB
  float* Cc = (float*)(aux + 280576);          // 256 KiB: C[tok][4][4]
  float* ST = (float*)(aux + 542720);          // 1.25 MiB: stats[tok][80]
  short* TMf = (short*)(aux + 2097152);        // 192 KiB fragment tables
  float* TDs = (float*)(aux + 2359296);        // 3 x 768 KiB table dots
  short* Wt = (short*)d_out;  // recomputed every call, overwritten at end

  dim3 tb(256);
  prep_pack<<<32, tb, 0, stream>>>(W_m, W_r, W_b, dyn_gamma, norm_gamma,
                                   norm_beta, gwm, gwr, gwb, rb);
  prep_tmf<<<dim3(16, 3), tb, 0, stream>>>(gwm, gwr, gwb, TMf);
  prep_sums<<<4, dim3(64), 0, stream>>>(W_m, W_r, W_b, dyn_gamma, S0w, T0d);
  transpose_wblk<<<dim3(32, 32, 4), tb, 0, stream>>>(Wblk, norm_gamma, Wt);
  row_sums<<<dim3(512, 4), tb, 0, stream>>>(Wt, rb, bblk, E0, E1);
  width0_kernel<<<1024, tb, 0, stream>>>(x, b0, hnorm, tst, Cc, ST, A_m, A_r,
                                         gwm, gwr, s_a, S0w);
  for (int i = 0; i < LL; i++) {
    gemm_kernel<<<512, dim3(512), 0, stream>>>(
        hnorm, Wt + (size_t)i * DD * DD, tst, E0 + i * DD, E1 + i * DD,
        h2s + (size_t)i * NTOK * DD);
    if (i < LL - 1) {
      table_dots<<<256, dim3(64), 0, stream>>>(
          h2s + (size_t)i * NTOK * DD, TMf, TDs + (size_t)i * NTOK * 48);
      if (i == 0)
        fused_dw<0><<<1024, tb, 0, stream>>>(h2s, b0, hnorm, tst, Cc, ST, TDs,
                                             Bp, s_b, A_m, A_r, s_a, S0w, T0d);
      else if (i == 1)
        fused_dw<1><<<1024, tb, 0, stream>>>(h2s, b0, hnorm, tst, Cc, ST, TDs,
                                             Bp, s_b, A_m, A_r, s_a, S0w, T0d);
      else
        fused_dw<2><<<1024, tb, 0, stream>>>(h2s, b0, hnorm, tst, Cc, ST, TDs,
                                             Bp, s_b, A_m, A_r, s_a, S0w, T0d);
    } else {
      depth_last<<<1024, tb, 0, stream>>>(h2s, b0, out, Cc, Bp, s_b, T0d, gwb);
    }
  }
}

// Round 17
// 327.976 us; speedup vs baseline: 1.0905x; 1.0905x over previous
//
#include <hip/hip_runtime.h>
#include <hip/hip_bf16.h>

// HCNet: L=4 hyper-connection blocks, N=4, D=2048, B*T=4096 tokens.
// FINAL (champion, ~325us, reproduced 3x): basis decomposition (H never
// materialized; per-token 4xK coefficient matrix + Gram/table-dot algebra),
// LN folded into GEMM epilogue, bf16 MFMA GEMM (128^2 tile, counted-vmcnt
// 2-phase, XOR-swizzled LDS, XCD-swizzled grid).
// Bracketed ceilings: gemm 43us (5 structural variants tried, all worse);
// fused_dw 30us (MFMA-stats, 2-wave split, table-dot pipeline all regressed).

#define DD 2048
#define NN 4
#define LL 4
#define NTOK 4096
#define EPSF 1e-5f
#define STS 80  // ST row stride (floats)

typedef __attribute__((ext_vector_type(8))) short bf16x8;
typedef __attribute__((ext_vector_type(4))) float f32x4;
typedef __attribute__((ext_vector_type(2))) float f32x2;

__device__ __forceinline__ float bf2f(short u) {
  union { unsigned int i; float f; } v;
  v.i = ((unsigned int)(unsigned short)u) << 16;
  return v.f;
}
__device__ __forceinline__ short f2bf(float f) {
  __hip_bfloat16 h = __float2bfloat16(f);
  short s;
  __builtin_memcpy(&s, &h, 2);
  return s;
}
__device__ __forceinline__ float wred(float v) {
#pragma unroll
  for (int off = 32; off > 0; off >>= 1) v += __shfl_xor(v, off, 64);
  return v;
}
__device__ __forceinline__ void ld16(const void* g, void* l) {
  __builtin_amdgcn_global_load_lds(
      (const __attribute__((address_space(1))) void*)g,
      (__attribute__((address_space(3))) void*)l, 16, 0, 0);
}
__host__ __device__ constexpr int pofs(int k, int l) {
  return k == 0 ? 20 + l * 5
       : k == 1 ? 40 + (l - 1) * 5
       : k == 2 ? 55 + (l - 2) * 5
                : 65;
}

// ---------------- prep: gamma-scaled bf16 tables + beta/gamma ratio ---------
__global__ __launch_bounds__(256) void prep_pack(
    const float* __restrict__ W_m, const float* __restrict__ W_r,
    const float* __restrict__ W_b, const float* __restrict__ dyn_gamma,
    const float* __restrict__ norm_gamma, const float* __restrict__ norm_beta,
    short* __restrict__ gwm, short* __restrict__ gwr, short* __restrict__ gwb,
    float* __restrict__ rb) {
  const int i = blockIdx.x * 256 + threadIdx.x;  // over L*D = 8192
  const float g = dyn_gamma[i];
  gwm[i] = f2bf(g * W_m[i]);
  f32x4 r = *(const f32x4*)(W_r + (size_t)i * 4);
  f32x4 b = *(const f32x4*)(W_b + (size_t)i * 4);
  short ro[4], bo[4];
#pragma unroll
  for (int k = 0; k < 4; k++) { ro[k] = f2bf(g * r[k]); bo[k] = f2bf(g * b[k]); }
  *(unsigned long long*)(gwr + (size_t)i * 4) = *(unsigned long long*)ro;
  *(unsigned long long*)(gwb + (size_t)i * 4) = *(unsigned long long*)bo;
  rb[i] = norm_beta[i] / norm_gamma[i];
}

// ---------------- token-independent sums S0w[l][5], T0d[l][4] ---------------
__global__ __launch_bounds__(64) void prep_sums(
    const float* __restrict__ W_m, const float* __restrict__ W_r,
    const float* __restrict__ W_b, const float* __restrict__ dyn_gamma,
    float* __restrict__ S0w, float* __restrict__ T0d) {
  const int l = blockIdx.x;
  const int lane = threadIdx.x;
  float s[5] = {0, 0, 0, 0, 0}, t[4] = {0, 0, 0, 0};
  for (int d = lane; d < DD; d += 64) {
    const float g = dyn_gamma[l * DD + d];
    s[0] += g * W_m[l * DD + d];
    f32x4 r = *(const f32x4*)(W_r + ((size_t)l * DD + d) * 4);
    f32x4 b = *(const f32x4*)(W_b + ((size_t)l * DD + d) * 4);
#pragma unroll
    for (int m = 0; m < 4; m++) { s[1 + m] += g * r[m]; t[m] += g * b[m]; }
  }
#pragma unroll
  for (int m = 0; m < 5; m++) s[m] = wred(s[m]);
#pragma unroll
  for (int n = 0; n < 4; n++) t[n] = wred(t[n]);
  if (lane == 0) {
#pragma unroll
    for (int m = 0; m < 5; m++) S0w[l * 5 + m] = s[m];
#pragma unroll
    for (int n = 0; n < 4; n++) T0d[l * 4 + n] = t[n];
  }
}

// ------- transpose Wblk[l][d][e] (f32) -> Wt[l][e][d] = norm_g[d]*W (bf16) --
__global__ __launch_bounds__(256) void transpose_wblk(
    const float* __restrict__ W, const float* __restrict__ norm_gamma,
    short* __restrict__ Wt) {
  __shared__ float tile[64][65];
  const int blk = blockIdx.z;
  const int c0 = blockIdx.x * 64;
  const int r0 = blockIdx.y * 64;
  const float* Ws = W + (size_t)blk * DD * DD;
  short* Wd = Wt + (size_t)blk * DD * DD;
  const int tx = threadIdx.x & 63, ty = threadIdx.x >> 6;
#pragma unroll
  for (int r = 0; r < 16; r++) {
    const int row = ty + r * 4;
    tile[row][tx] = Ws[(size_t)(r0 + row) * DD + c0 + tx];
  }
  const float gsc = norm_gamma[blk * DD + r0 + tx];
  __syncthreads();
#pragma unroll
  for (int r = 0; r < 16; r++) {
    const int row = ty + r * 4;
    Wd[(size_t)(c0 + row) * DD + r0 + tx] = f2bf(tile[tx][row] * gsc);
  }
}

// ---------------- row sums of Wt': E1 = sum_d Wt', E0 = sum_d rb*Wt' + bias -
__global__ __launch_bounds__(256) void row_sums(
    const short* __restrict__ Wt, const float* __restrict__ rb,
    const float* __restrict__ bblk, float* __restrict__ E0,
    float* __restrict__ E1) {
  const int l = blockIdx.y;
  const int e = blockIdx.x * 4 + (threadIdx.x >> 6);
  const int lane = threadIdx.x & 63;
  const short* row = Wt + ((size_t)l * DD + e) * DD;
  const float* rbl = rb + l * DD;
  float s1 = 0.f, s0 = 0.f;
#pragma unroll
  for (int it = 0; it < 4; it++) {
    const int d0 = lane * 8 + it * 512;
    bf16x8 w = *(const bf16x8*)(row + d0);
    f32x4 r0 = *(const f32x4*)(rbl + d0), r1 = *(const f32x4*)(rbl + d0 + 4);
#pragma unroll
    for (int q = 0; q < 8; q++) {
      const float wq = bf2f(w[q]);
      s1 += wq;
      s0 += wq * ((q < 4) ? r0[q] : r1[q - 4]);
    }
  }
  s1 = wred(s1); s0 = wred(s0);
  if (lane == 0) {
    E1[l * DD + e] = s1;
    E0[l * DD + e] = s0 + bblk[l * DD + e];
  }
}

// ---------------- width0: x-dots + block-0 coefficients + hnorm -------------
__global__ __launch_bounds__(256) void width0_kernel(
    const float* __restrict__ x, short* __restrict__ b0,
    short* __restrict__ hout, f32x2* __restrict__ tst, float* __restrict__ Cc,
    float* __restrict__ ST, const float* __restrict__ A_m,
    const float* __restrict__ A_r, const short* __restrict__ gwm,
    const short* __restrict__ gwr, const float* __restrict__ s_a,
    const float* __restrict__ S0w) {
  const int wave = threadIdx.x >> 6;
  const int lane = threadIdx.x & 63;
  const int tok = blockIdx.x * 4 + wave;
  const float* xr = x + (size_t)tok * DD;
  short* b0t = b0 + (size_t)tok * DD;

  bf16x8 xb[4];
#pragma unroll
  for (int j = 0; j < 4; j++) {
    const int d0 = lane * 8 + j * 512;
    f32x4 a = *(const f32x4*)(xr + d0);
    f32x4 b = *(const f32x4*)(xr + d0 + 4);
    bf16x8 p;
#pragma unroll
    for (int q = 0; q < 4; q++) { p[q] = f2bf(a[q]); p[4 + q] = f2bf(b[q]); }
    xb[j] = p;
    *(bf16x8*)(b0t + d0) = p;
  }

  float o = 0.f, qq = 0.f, P0[4][5];
#pragma unroll
  for (int l = 0; l < 4; l++)
#pragma unroll
    for (int m = 0; m < 5; m++) P0[l][m] = 0.f;

#pragma unroll
  for (int j = 0; j < 4; j++) {
    const int d0 = lane * 8 + j * 512;
    bf16x8 wmv[4], wrv[4][4];
#pragma unroll
    for (int l = 0; l < 4; l++) {
      wmv[l] = *(const bf16x8*)(gwm + l * DD + d0);
#pragma unroll
      for (int p = 0; p < 4; p++)
        wrv[l][p] = *(const bf16x8*)(gwr + ((size_t)l * DD + d0 + 2 * p) * 4);
    }
#pragma unroll
    for (int q = 0; q < 8; q++) {
      const float hv = bf2f(xb[j][q]);
      o += hv; qq += hv * hv;
#pragma unroll
      for (int l = 0; l < 4; l++) {
        P0[l][0] += hv * bf2f(wmv[l][q]);
#pragma unroll
        for (int m = 0; m < 4; m++)
          P0[l][1 + m] += hv * bf2f(wrv[l][q >> 1][(q & 1) * 4 + m]);
      }
    }
  }
  o = wred(o); qq = wred(qq);
#pragma unroll
  for (int l = 0; l < 4; l++)
#pragma unroll
    for (int m = 0; m < 5; m++) P0[l][m] = wred(P0[l][m]);

  // block-0 width coefficients (all H rows = x)
  const float sa = s_a[0];
  const float mu = o * (1.f / DD);
  const float inv = rsqrtf(qq * (1.f / DD) - mu * mu + EPSF);
  const float t0 = tanhf(inv * (P0[0][0] - mu * S0w[0]));
  float tm[4];
#pragma unroll
  for (int m = 0; m < 4; m++)
    tm[m] = tanhf(inv * (P0[0][1 + m] - mu * S0w[1 + m]));
  float amSum = 0.f, arCol[4] = {0, 0, 0, 0};
#pragma unroll
  for (int n = 0; n < 4; n++) {
    amSum += A_m[n] + sa * t0;
#pragma unroll
    for (int m = 0; m < 4; m++) arCol[m] += A_r[n * 4 + m] + sa * tm[m];
  }

  if (lane == 0) {
    const float sh = amSum * o;
    const float sh2 = amSum * amSum * qq;
    const float mu2 = sh * (1.f / DD);
    const float inv2 = rsqrtf(sh2 * (1.f / DD) - mu2 * mu2 + EPSF);
    f32x2 t; t[0] = inv2; t[1] = mu2 * inv2;
    tst[tok] = t;
    float* STt = ST + (size_t)tok * STS;
    STt[0] = o;
    STt[4] = qq;  // G[0][0]
#pragma unroll
    for (int l = 0; l < 4; l++)
#pragma unroll
      for (int m = 0; m < 5; m++) STt[pofs(0, l) + m] = P0[l][m];
    float* Ct = Cc + (size_t)tok * 16;
#pragma unroll
    for (int n = 0; n < 4; n++) Ct[n * 4] = arCol[n];
  }

  short* hw = hout + (size_t)tok * DD;
#pragma unroll
  for (int j = 0; j < 4; j++) {
    const int d0 = lane * 8 + j * 512;
    bf16x8 ho;
#pragma unroll
    for (int q = 0; q < 8; q++) ho[q] = f2bf(amSum * bf2f(xb[j][q]));
    *(bf16x8*)(hw + d0) = ho;
  }
}

// ---------------- block GEMM: h2 = LN-folded(h @ Wt') -----------------------
// Counted-vmcnt pipeline: STAGE(kt+1) issued first, vmcnt(4) waits only for
// stage(kt), raw barriers; prefetch loads stay in flight across the barrier.
__global__ __launch_bounds__(512) void gemm_kernel(
    const short* __restrict__ A, const short* __restrict__ Bt,
    const f32x2* __restrict__ tst, const float* __restrict__ E0,
    const float* __restrict__ E1, short* __restrict__ C) {
  __shared__ short lA[2][128 * 64];
  __shared__ short lB[2][128 * 64];
  const int tid = threadIdx.x;
  const int lane = tid & 63;
  const int wave = tid >> 6;
  const int bid = blockIdx.x;
  const int wg = (bid & 7) * 64 + (bid >> 3);
  const int m0 = (wg & 31) * 128, n0 = (wg >> 5) * 128;
  const int wm = wave >> 2;
  const int wn = wave & 3;

  f32x4 acc[4][2] = {};

#define STAGE(buf, kt)                                                        \
  {                                                                           \
    const int k0 = (kt) * 64;                                                 \
    _Pragma("unroll") for (int c = 0; c < 2; c++) {                           \
      const int idx = c * 512 + tid;                                          \
      const int row = idx >> 3;                                               \
      const int colsw = (((idx & 7) ^ (row & 7)) * 8);                        \
      ld16(A + (size_t)(m0 + row) * DD + k0 + colsw,                          \
           (char*)&lA[buf][0] + idx * 16);                                    \
      ld16(Bt + (size_t)(n0 + row) * DD + k0 + colsw,                         \
           (char*)&lB[buf][0] + idx * 16);                                    \
    }                                                                         \
  }

#define COMPUTE(cur)                                                          \
  {                                                                           \
    const char* bufA = (const char*)&lA[cur][0];                              \
    const char* bufB = (const char*)&lB[cur][0];                              \
    _Pragma("unroll") for (int kk = 0; kk < 2; ++kk) {                        \
      const int gsw = (kk * 64 + (lane >> 4) * 16) ^ ((lane & 7) << 4);       \
      bf16x8 af[4], bfr[2];                                                   \
      _Pragma("unroll") for (int m = 0; m < 4; m++) {                         \
        const int r = wm * 64 + m * 16 + (lane & 15);                         \
        af[m] = *(const bf16x8*)(bufA + r * 128 + gsw);                       \
      }                                                                       \
      _Pragma("unroll") for (int n = 0; n < 2; n++) {                         \
        const int r = wn * 32 + n * 16 + (lane & 15);                         \
        bfr[n] = *(const bf16x8*)(bufB + r * 128 + gsw);                      \
      }                                                                       \
      __builtin_amdgcn_s_setprio(1);                                          \
      _Pragma("unroll") for (int m = 0; m < 4; m++)                           \
        _Pragma("unroll") for (int n = 0; n < 2; n++)                         \
          acc[m][n] = __builtin_amdgcn_mfma_f32_16x16x32_bf16(                \
              af[m], bfr[n], acc[m][n], 0, 0, 0);                             \
      __builtin_amdgcn_s_setprio(0);                                          \
    }                                                                         \
  }

  STAGE(0, 0);
  for (int kt = 0; kt < 31; ++kt) {
    const int cur = kt & 1;
    STAGE(cur ^ 1, kt + 1);                       // 4 loads -> 8 outstanding
    asm volatile("s_waitcnt vmcnt(4)" ::: "memory");  // stage(kt) landed
    asm volatile("s_barrier" ::: "memory");           // all waves agree
    COMPUTE(cur);
    asm volatile("s_barrier" ::: "memory");           // reads of buf cur done
  }
  asm volatile("s_waitcnt vmcnt(0)" ::: "memory");
  asm volatile("s_barrier" ::: "memory");
  COMPUTE(1);
#undef STAGE
#undef COMPUTE

  float e0c[2], e1c[2];
  int cols[2];
#pragma unroll
  for (int n = 0; n < 2; n++) {
    cols[n] = n0 + wn * 32 + n * 16 + (lane & 15);
    e0c[n] = E0[cols[n]];
    e1c[n] = E1[cols[n]];
  }
#pragma unroll
  for (int m = 0; m < 4; m++) {
    const int rbase = m0 + wm * 64 + m * 16 + ((lane >> 4) << 2);
#pragma unroll
    for (int j = 0; j < 4; j++) {
      const int row = rbase + j;
      const f32x2 iv = tst[row];
#pragma unroll
      for (int n = 0; n < 2; n++)
        C[(size_t)row * DD + cols[n]] =
            f2bf(iv[0] * acc[m][n][j] - iv[1] * e1c[n] + e0c[n]);
    }
  }
}

// ---------------- fused depth(I) + width(I+1) in basis form (1 wave/token) --
template <int I>
__global__ __launch_bounds__(256) void fused_dw(
    const short* __restrict__ h2s, const short* __restrict__ b0,
    short* __restrict__ hout, f32x2* __restrict__ tst, float* __restrict__ Cc,
    float* __restrict__ ST, const float* __restrict__ Bp,
    const float* __restrict__ s_b, const float* __restrict__ A_m,
    const float* __restrict__ A_r, const float* __restrict__ s_a,
    const float* __restrict__ S0w, const float* __restrict__ T0d,
    const short* __restrict__ gwm, const short* __restrict__ gwr,
    const short* __restrict__ gwb) {
  constexpr int NB = I + 1;   // width block index
  constexpr int NP = 3 - I;   // # of gw tables to dot (l = NB..3)
  const int wave = threadIdx.x >> 6;
  const int lane = threadIdx.x & 63;
  const int tok = blockIdx.x * 4 + wave;

  const short* vt = h2s + ((size_t)I * NTOK + tok) * DD;
  const short* bases[I + 1];
  bases[0] = b0 + (size_t)tok * DD;
#pragma unroll
  for (int k = 1; k <= I; k++)
    bases[k] = h2s + ((size_t)(k - 1) * NTOK + tok) * DD;

  bf16x8 h2r[4];
#pragma unroll
  for (int j = 0; j < 4; j++)
    h2r[j] = *(const bf16x8*)(vt + lane * 8 + j * 512);

  // ---- phase 1: dots on v = h2^I ----
  float o = 0.f;
  float Gr[I + 2] = {};   // Gr[k]=v.b_k (k<=I), Gr[I+1]=v.v
  float Tb[4] = {0, 0, 0, 0};
  float Pn[NP][5];
#pragma unroll
  for (int li = 0; li < NP; li++)
#pragma unroll
    for (int m = 0; m < 5; m++) Pn[li][m] = 0.f;

#pragma unroll
  for (int j = 0; j < 4; j++) {
    const int d0 = lane * 8 + j * 512;
    bf16x8 bsv[I + 1];
#pragma unroll
    for (int k = 0; k <= I; k++) bsv[k] = *(const bf16x8*)(bases[k] + d0);
    bf16x8 wbv[4];
#pragma unroll
    for (int p = 0; p < 4; p++)
      wbv[p] = *(const bf16x8*)(gwb + ((size_t)I * DD + d0 + 2 * p) * 4);
    bf16x8 wmv[NP], wrv[NP][4];
#pragma unroll
    for (int li = 0; li < NP; li++) {
      const int l = NB + li;
      wmv[li] = *(const bf16x8*)(gwm + l * DD + d0);
#pragma unroll
      for (int p = 0; p < 4; p++)
        wrv[li][p] = *(const bf16x8*)(gwr + ((size_t)l * DD + d0 + 2 * p) * 4);
    }
#pragma unroll
    for (int q = 0; q < 8; q++) {
      const float hv = bf2f(h2r[j][q]);
      o += hv;
      Gr[I + 1] += hv * hv;
#pragma unroll
      for (int k = 0; k <= I; k++) Gr[k] += hv * bf2f(bsv[k][q]);
#pragma unroll
      for (int n = 0; n < 4; n++)
        Tb[n] += hv * bf2f(wbv[q >> 1][(q & 1) * 4 + n]);
#pragma unroll
      for (int li = 0; li < NP; li++) {
        Pn[li][0] += hv * bf2f(wmv[li][q]);
#pragma unroll
        for (int m = 0; m < 4; m++)
          Pn[li][1 + m] += hv * bf2f(wrv[li][q >> 1][(q & 1) * 4 + m]);
      }
    }
  }
  o = wred(o);
#pragma unroll
  for (int k = 0; k <= I + 1; k++) Gr[k] = wred(Gr[k]);
#pragma unroll
  for (int n = 0; n < 4; n++) Tb[n] = wred(Tb[n]);
#pragma unroll
  for (int li = 0; li < NP; li++)
#pragma unroll
    for (int m = 0; m < 5; m++) Pn[li][m] = wred(Pn[li][m]);

  // ---- phase 2: coefficient algebra (wave-uniform) ----
  float* STt = ST + (size_t)tok * STS;
  float* Ct = Cc + (size_t)tok * 16;
  float ofull[I + 2], Gf[I + 2][I + 2], Pf[I + 2][5], Cp[4][I + 2];
#pragma unroll
  for (int k = 0; k <= I; k++) ofull[k] = STt[k];
  ofull[I + 1] = o;
#pragma unroll
  for (int k = 0; k <= I; k++)
#pragma unroll
    for (int j2 = 0; j2 <= I; j2++) Gf[k][j2] = STt[4 + k * 4 + j2];
#pragma unroll
  for (int k = 0; k <= I; k++) { Gf[k][I + 1] = Gr[k]; Gf[I + 1][k] = Gr[k]; }
  Gf[I + 1][I + 1] = Gr[I + 1];
#pragma unroll
  for (int k = 0; k <= I; k++)
#pragma unroll
    for (int m = 0; m < 5; m++) Pf[k][m] = STt[pofs(k, NB) + m];
#pragma unroll
  for (int m = 0; m < 5; m++) Pf[I + 1][m] = Pn[0][m];
#pragma unroll
  for (int n = 0; n < 4; n++)
#pragma unroll
    for (int k = 0; k <= I; k++) Cp[n][k] = Ct[n * 4 + k];

  // depth coefficients Bv (block I)
  {
    const float mu2 = o * (1.f / DD);
    const float inv2 = rsqrtf(Gr[I + 1] * (1.f / DD) - mu2 * mu2 + EPSF);
    const float sb = s_b[I];
#pragma unroll
    for (int n = 0; n < 4; n++)
      Cp[n][I + 1] = Bp[I * 4 + n] +
                     sb * tanhf(inv2 * (Tb[n] - mu2 * T0d[I * 4 + n]));
  }

  // width coefficients Am/Ar (block NB) from Gram-expanded stats
  const float sa = s_a[NB];
  float Am[4], Ar[4][4];
#pragma unroll
  for (int n = 0; n < 4; n++) {
    float sH = 0.f, sH2 = 0.f;
#pragma unroll
    for (int k = 0; k <= I + 1; k++) {
      sH += Cp[n][k] * ofull[k];
#pragma unroll
      for (int j2 = 0; j2 <= I + 1; j2++)
        sH2 += Cp[n][k] * Cp[n][j2] * Gf[k][j2];
    }
    const float mu = sH * (1.f / DD);
    const float inv = rsqrtf(sH2 * (1.f / DD) - mu * mu + EPSF);
    float S1[5];
#pragma unroll
    for (int m = 0; m < 5; m++) {
      S1[m] = 0.f;
#pragma unroll
      for (int k = 0; k <= I + 1; k++) S1[m] += Cp[n][k] * Pf[k][m];
    }
    Am[n] = A_m[NB * 4 + n] +
            sa * tanhf(inv * (S1[0] - mu * S0w[NB * 5 + 0]));
#pragma unroll
    for (int m = 0; m < 4; m++)
      Ar[n][m] = A_r[NB * 16 + n * 4 + m] +
                 sa * tanhf(inv * (S1[1 + m] - mu * S0w[NB * 5 + 1 + m]));
  }

  // new coefficient matrix and hnorm combo coefficients
  float Cn[4][I + 2], hc[I + 2];
#pragma unroll
  for (int k = 0; k <= I + 1; k++) {
    hc[k] = 0.f;
#pragma unroll
    for (int n = 0; n < 4; n++) hc[k] += Am[n] * Cp[n][k];
  }
#pragma unroll
  for (int mr = 0; mr < 4; mr++)
#pragma unroll
    for (int k = 0; k <= I + 1; k++) {
      float acc = 0.f;
#pragma unroll
      for (int n = 0; n < 4; n++) acc += Ar[n][mr] * Cp[n][k];
      Cn[mr][k] = acc;
    }

  if (lane == 0) {
    float sh = 0.f, sh2 = 0.f;
#pragma unroll
    for (int k = 0; k <= I + 1; k++) {
      sh += hc[k] * ofull[k];
#pragma unroll
      for (int j2 = 0; j2 <= I + 1; j2++) sh2 += hc[k] * hc[j2] * Gf[k][j2];
    }
    const float mu = sh * (1.f / DD);
    const float inv = rsqrtf(sh2 * (1.f / DD) - mu * mu + EPSF);
    f32x2 t; t[0] = inv; t[1] = mu * inv;
    tst[tok] = t;
    STt[I + 1] = o;
#pragma unroll
    for (int k = 0; k <= I + 1; k++) {
      STt[4 + (I + 1) * 4 + k] = Gf[I + 1][k];
      STt[4 + k * 4 + (I + 1)] = Gf[k][I + 1];
    }
#pragma unroll
    for (int li = 1; li < NP; li++)
#pragma unroll
      for (int m = 0; m < 5; m++) STt[pofs(I + 1, NB + li) + m] = Pn[li][m];
#pragma unroll
    for (int n = 0; n < 4; n++)
#pragma unroll
      for (int k = 0; k <= I + 1; k++) Ct[n * 4 + k] = Cn[n][k];
  }

  // ---- phase 3: hnorm = sum_k hc[k] * b_k ----
  short* hw = hout + (size_t)tok * DD;
#pragma unroll
  for (int j = 0; j < 4; j++) {
    const int d0 = lane * 8 + j * 512;
    bf16x8 bsv[I + 1];
#pragma unroll
    for (int k = 0; k <= I; k++) bsv[k] = *(const bf16x8*)(bases[k] + d0);
    bf16x8 ho;
#pragma unroll
    for (int q = 0; q < 8; q++) {
      float a = hc[I + 1] * bf2f(h2r[j][q]);
#pragma unroll
      for (int k = 0; k <= I; k++) a += hc[k] * bf2f(bsv[k][q]);
      ho[q] = f2bf(a);
    }
    *(bf16x8*)(hw + d0) = ho;
  }
}

// ---------------- final depth (block 3) + output combo ----------------------
__global__ __launch_bounds__(256) void depth_last(
    const short* __restrict__ h2s, const short* __restrict__ b0,
    float* __restrict__ out, const float* __restrict__ Cc,
    const float* __restrict__ Bp, const float* __restrict__ s_b,
    const float* __restrict__ T0d, const short* __restrict__ gwb) {
  const int wave = threadIdx.x >> 6;
  const int lane = threadIdx.x & 63;
  const int tok = blockIdx.x * 4 + wave;
  const short* vt = h2s + ((size_t)3 * NTOK + tok) * DD;

  bf16x8 h2r[4];
  float s1 = 0.f, s2 = 0.f, Tb[4] = {0, 0, 0, 0};
#pragma unroll
  for (int j = 0; j < 4; j++) {
    const int d0 = lane * 8 + j * 512;
    h2r[j] = *(const bf16x8*)(vt + d0);
    bf16x8 wbv[4];
#pragma unroll
    for (int p = 0; p < 4; p++)
      wbv[p] = *(const bf16x8*)(gwb + ((size_t)3 * DD + d0 + 2 * p) * 4);
#pragma unroll
    for (int q = 0; q < 8; q++) {
      const float hv = bf2f(h2r[j][q]);
      s1 += hv; s2 += hv * hv;
#pragma unroll
      for (int n = 0; n < 4; n++)
        Tb[n] += hv * bf2f(wbv[q >> 1][(q & 1) * 4 + n]);
    }
  }
  s1 = wred(s1); s2 = wred(s2);
#pragma unroll
  for (int n = 0; n < 4; n++) Tb[n] = wred(Tb[n]);

  const float mu = s1 * (1.f / DD);
  const float inv = rsqrtf(s2 * (1.f / DD) - mu * mu + EPSF);
  const float sb = s_b[3];
  float bsum = 0.f;
#pragma unroll
  for (int n = 0; n < 4; n++)
    bsum += Bp[12 + n] + sb * tanhf(inv * (Tb[n] - mu * T0d[12 + n]));

  const float* Ct = Cc + (size_t)tok * 16;
  float e[4];
#pragma unroll
  for (int k = 0; k < 4; k++) {
    e[k] = 0.f;
#pragma unroll
    for (int n = 0; n < 4; n++) e[k] += Ct[n * 4 + k];
  }

  const short* bases[4];
  bases[0] = b0 + (size_t)tok * DD;
#pragma unroll
  for (int k = 1; k < 4; k++)
    bases[k] = h2s + ((size_t)(k - 1) * NTOK + tok) * DD;

  float* orow = out + (size_t)tok * DD;
#pragma unroll
  for (int j = 0; j < 4; j++) {
    const int d0 = lane * 8 + j * 512;
    bf16x8 bsv[4];
#pragma unroll
    for (int k = 0; k < 4; k++) bsv[k] = *(const bf16x8*)(bases[k] + d0);
    f32x4 o0, o1;
#pragma unroll
    for (int q = 0; q < 8; q++) {
      float s = bsum * bf2f(h2r[j][q]);
#pragma unroll
      for (int k = 0; k < 4; k++) s += e[k] * bf2f(bsv[k][q]);
      if (q < 4) o0[q] = s; else o1[q - 4] = s;
    }
    *(f32x4*)(orow + d0) = o0;
    *(f32x4*)(orow + d0 + 4) = o1;
  }
}

extern "C" void kernel_launch(void* const* d_in, const int* in_sizes, int n_in,
                              void* d_out, int out_size, void* d_ws,
                              size_t ws_size, hipStream_t stream) {
  const float* x = (const float*)d_in[0];
  const float* A_m = (const float*)d_in[1];
  const float* A_r = (const float*)d_in[2];
  const float* Bp = (const float*)d_in[3];
  const float* W_m = (const float*)d_in[4];
  const float* W_r = (const float*)d_in[5];
  const float* W_b = (const float*)d_in[6];
  const float* s_a = (const float*)d_in[7];
  const float* s_b = (const float*)d_in[8];
  const float* dyn_gamma = (const float*)d_in[9];
  const float* norm_gamma = (const float*)d_in[10];
  const float* norm_beta = (const float*)d_in[11];
  const float* Wblk = (const float*)d_in[12];
  const float* bblk = (const float*)d_in[13];
  float* out = (float*)d_out;

  char* ws = (char*)d_ws;
  short* b0 = (short*)(ws);                    // 16 MiB: bf16 copy of x
  short* h2s = (short*)(ws + 16777216);        // 4 slots x 16 MiB
  short* hnorm = (short*)(ws + 83886080);      // 16 MiB
  char* aux = ws + 100663296;
  short* gwm = (short*)(aux);                  // 16 KiB
  short* gwr = (short*)(aux + 16384);          // 64 KiB
  short* gwb = (short*)(aux + 81920);          // 64 KiB
  float* rb = (float*)(aux + 147456);          // 32 KiB
  float* S0w = (float*)(aux + 180224);
  float* T0d = (float*)(aux + 181248);
  f32x2* tst = (f32x2*)(aux + 182272);         // 32 KiB
  float* E0 = (float*)(aux + 215040);          // 32 KiB
  float* E1 = (float*)(aux + 247808);          // 32 KiB
  float* Cc = (float*)(aux + 280576);          // 256 KiB: C[tok][4][4]
  float* ST = (float*)(aux + 542720);          // 1.25 MiB: stats[tok][80]
  short* Wt = (short*)d_out;  // recomputed every call, overwritten at end

  dim3 tb(256);
  prep_pack<<<32, tb, 0, stream>>>(W_m, W_r, W_b, dyn_gamma, norm_gamma,
                                   norm_beta, gwm, gwr, gwb, rb);
  prep_sums<<<4, dim3(64), 0, stream>>>(W_m, W_r, W_b, dyn_gamma, S0w, T0d);
  transpose_wblk<<<dim3(32, 32, 4), tb, 0, stream>>>(Wblk, norm_gamma, Wt);
  row_sums<<<dim3(512, 4), tb, 0, stream>>>(Wt, rb, bblk, E0, E1);
  width0_kernel<<<1024, tb, 0, stream>>>(x, b0, hnorm, tst, Cc, ST, A_m, A_r,
                                         gwm, gwr, s_a, S0w);
  for (int i = 0; i < LL; i++) {
    gemm_kernel<<<512, dim3(512), 0, stream>>>(
        hnorm, Wt + (size_t)i * DD * DD, tst, E0 + i * DD, E1 + i * DD,
        h2s + (size_t)i * NTOK * DD);
    if (i == 0)
      fused_dw<0><<<1024, tb, 0, stream>>>(h2s, b0, hnorm, tst, Cc, ST, Bp,
                                           s_b, A_m, A_r, s_a, S0w, T0d, gwm,
                                           gwr, gwb);
    else if (i == 1)
      fused_dw<1><<<1024, tb, 0, stream>>>(h2s, b0, hnorm, tst, Cc, ST, Bp,
                                           s_b, A_m, A_r, s_a, S0w, T0d, gwm,
                                           gwr, gwb);
    else if (i == 2)
      fused_dw<2><<<1024, tb, 0, stream>>>(h2s, b0, hnorm, tst, Cc, ST, Bp,
                                           s_b, A_m, A_r, s_a, S0w, T0d, gwm,
                                           gwr, gwb);
    else
      depth_last<<<1024, tb, 0, stream>>>(h2s, b0, out, Cc, Bp, s_b, T0d, gwb);
  }
}